// Round 15
// baseline (215.771 us; speedup 1.0000x reference)
//
#include <hip/hip_runtime.h>
#include <hip/hip_bf16.h>
#include <math.h>

#define N_NODES   100000
#define N_EDGES   3200000
#define NODE_DIM  128
#define HID       16
#define N_GRAPHS  256

// Bucketing: 64 nodes/bucket. ebuf is BUCKET-MAJOR. Count AND scatter use the
// XCD-swizzled chunk assignment (r7/r10 wins). Count writes its histogram
// directly bucket-major (r10), zeroes pool/cnt (r12/r13), uses 4-way
// sub-histograms (r14) and 8-edge atomic-ILP grouping + NT loads (r15).
// degxw's hist loop is 4-edge grouped (r15, same mechanism). Scatter groups
// 8 edges per iteration (r14). Gather uses ds_add_u64 with biased low halves
// (r8). Scan stays two kernels (r12: kernel boundary < software barrier).
#define BSHIFT    6
#define NPB       64                                // nodes per bucket
#define NBUCK     ((N_NODES + NPB - 1) >> BSHIFT)   // 1563
#define NBLK      256                               // chunks in count/scatter
#define TOT       (NBUCK * NBLK)                    // 400128
#define ACC64S    9                                 // u64 acc stride (8 + pad)

// Fixed-point scales.
#define FIX16  4096.0f          // 2^12 xws int16 scale
#define IFIX16 (1.0f/4096.0f)
#define FIXP   131072.0f        // 2^17 pool scale
#define IFIXP  (1.0f/131072.0f)

__device__ __forceinline__ short f2bf(float f) {
    unsigned u = __float_as_uint(f);
    unsigned r = (u + 0x7FFF + ((u >> 16) & 1)) >> 16;
    return (short)r;
}
__device__ __forceinline__ int fx(float v, float s) { return __float2int_rn(v * s); }

// Pack an int32 holding two int16 dims into a biased u64 addend:
// low half: (lo ^ 0x8000) = lo + 32768 in [0,65535] (never borrows);
// high half: hi (two's complement accumulation exact since low never carries).
__device__ __forceinline__ unsigned long long packA(int w) {
    return ((unsigned long long)(unsigned)(w >> 16) << 32)
         | (unsigned)((w & 0xFFFF) ^ 0x8000);
}

typedef __attribute__((ext_vector_type(8))) short bf16x8;
typedef __attribute__((ext_vector_type(4))) float f32x4;
typedef __attribute__((ext_vector_type(4))) int   i32x4;

// ---------------------------------------------------------------------------
// Pass A: per-chunk bucket histogram via 4-way LDS sub-hists (r14) with
// 8-edge atomic-ILP grouping + NT loads (r15), written DIRECTLY bucket-major:
// offT[k*NBLK + b] = count of bucket k in chunk b (XCD-swizzled b).
// Block 0 also zeroes pool/cnt (replaces the hipMemsetAsync dispatch).
// ---------------------------------------------------------------------------
__global__ __launch_bounds__(1024) void bucket_count(
    const int* __restrict__ dst, int* __restrict__ offT,
    int* __restrict__ pz, int nz, int E, int chunk)
{
    __shared__ int cnt4[4][NBUCK];       // 25 KB
    const int t = threadIdx.x;
    const int sub = t >> 8;
    const int b = (blockIdx.x & 7) * (NBLK >> 3) + (blockIdx.x >> 3);
    if (blockIdx.x == 0) {
        for (int i = t; i < nz; i += 1024) pz[i] = 0;
    }
    {
        int* cp = &cnt4[0][0];
        for (int i = t; i < 4 * NBUCK; i += 1024) cp[i] = 0;
    }
    __syncthreads();
    int e0 = b * chunk, e1 = min(E, e0 + chunk);
    if (e1 > e0) {
        const i32x4* d4 = (const i32x4*)dst;
        int i = (e0 >> 2) + t;
        const int iend = (e1 >> 2);
        for (; i + 1024 < iend; i += 2048) {
            i32x4 d0 = __builtin_nontemporal_load(&d4[i]);
            i32x4 d1 = __builtin_nontemporal_load(&d4[i + 1024]);
            atomicAdd(&cnt4[sub][d0[0] >> BSHIFT], 1);
            atomicAdd(&cnt4[sub][d0[1] >> BSHIFT], 1);
            atomicAdd(&cnt4[sub][d0[2] >> BSHIFT], 1);
            atomicAdd(&cnt4[sub][d0[3] >> BSHIFT], 1);
            atomicAdd(&cnt4[sub][d1[0] >> BSHIFT], 1);
            atomicAdd(&cnt4[sub][d1[1] >> BSHIFT], 1);
            atomicAdd(&cnt4[sub][d1[2] >> BSHIFT], 1);
            atomicAdd(&cnt4[sub][d1[3] >> BSHIFT], 1);
        }
        for (; i < iend; i += 1024) {
            i32x4 d = __builtin_nontemporal_load(&d4[i]);
            atomicAdd(&cnt4[sub][d[0] >> BSHIFT], 1);
            atomicAdd(&cnt4[sub][d[1] >> BSHIFT], 1);
            atomicAdd(&cnt4[sub][d[2] >> BSHIFT], 1);
            atomicAdd(&cnt4[sub][d[3] >> BSHIFT], 1);
        }
    }
    __syncthreads();
    for (int k = t; k < NBUCK; k += 1024)
        offT[k * NBLK + b] = cnt4[0][k] + cnt4[1][k] + cnt4[2][k] + cnt4[3][k];
}

// ---------------------------------------------------------------------------
// Scan step 1: per-2048-block sums.
// ---------------------------------------------------------------------------
__global__ __launch_bounds__(256) void scan_blocksum(
    const int* __restrict__ M, int* __restrict__ bsum, int n)
{
    __shared__ int red[256];
    int t = threadIdx.x;
    int base = blockIdx.x * 2048 + t * 8;
    int s = 0;
    #pragma unroll
    for (int k = 0; k < 8; ++k) { int i = base + k; if (i < n) s += M[i]; }
    red[t] = s; __syncthreads();
    for (int o = 128; o > 0; o >>= 1) {
        if (t < o) red[t] += red[t + o];
        __syncthreads();
    }
    if (t == 0) bsum[blockIdx.x] = red[0];
}

// ---------------------------------------------------------------------------
// Scan step 2 (fused top-level): exclusive prefix, in place.
// ---------------------------------------------------------------------------
__global__ __launch_bounds__(256) void scan_write2(
    int* __restrict__ M, const int* __restrict__ bsum, int n, int nb)
{
    __shared__ int tmp[256];
    __shared__ int tsum[256];
    int t = threadIdx.x;
    tmp[t] = (t < nb) ? bsum[t] : 0;
    __syncthreads();
    for (int o = 1; o < 256; o <<= 1) {
        int a = (t >= o) ? tmp[t - o] : 0;
        __syncthreads();
        tmp[t] += a;
        __syncthreads();
    }
    const int pre0 = (blockIdx.x > 0) ? tmp[blockIdx.x - 1] : 0;

    int base = blockIdx.x * 2048 + t * 8;
    int v[8]; int s = 0;
    #pragma unroll
    for (int k = 0; k < 8; ++k) { int i = base + k; v[k] = (i < n) ? M[i] : 0; s += v[k]; }
    tsum[t] = s; __syncthreads();
    int mine = s;
    for (int o = 1; o < 256; o <<= 1) {
        int a = (t >= o) ? tsum[t - o] : 0;
        __syncthreads();
        tsum[t] += a;
        __syncthreads();
    }
    int pre = pre0 + tsum[t] - mine;
    #pragma unroll
    for (int k = 0; k < 8; ++k) {
        int i = base + k;
        if (i < n) { M[i] = pre; pre += v[k]; }
    }
}

// ---------------------------------------------------------------------------
// Pass C: bin edges into bucket-major windows. XCD-swizzled chunk index;
// cursor init reads offT transposed (strided, L2-resident). NT loads on the
// coalesced read-once src/dst streams. 8 edges per iteration: all 8 cursor
// atomics issue back-to-back (latencies overlap), then all 8 stores.
// Payload: src | (dloc << 17).
// ---------------------------------------------------------------------------
__global__ __launch_bounds__(1024) void bucket_scatter(
    const int* __restrict__ src, const int* __restrict__ dst,
    const int* __restrict__ offT, int* __restrict__ ebuf, int E, int chunk)
{
    __shared__ int cur[NBUCK];
    const int t = threadIdx.x;
    const int b = (blockIdx.x & 7) * (NBLK >> 3) + (blockIdx.x >> 3);
    for (int k = t; k < NBUCK; k += 1024) cur[k] = offT[k * NBLK + b];
    __syncthreads();
    int e0 = b * chunk, e1 = min(E, e0 + chunk);
    if (e1 <= e0) return;
    const i32x4* d4 = (const i32x4*)dst;
    const i32x4* s4 = (const i32x4*)src;
    int i = (e0 >> 2) + t;
    const int iend = (e1 >> 2);
    for (; i + 1024 < iend; i += 2048) {
        i32x4 d0 = __builtin_nontemporal_load(&d4[i]);
        i32x4 s0 = __builtin_nontemporal_load(&s4[i]);
        i32x4 d1 = __builtin_nontemporal_load(&d4[i + 1024]);
        i32x4 s1 = __builtin_nontemporal_load(&s4[i + 1024]);
        int p0 = atomicAdd(&cur[d0[0] >> BSHIFT], 1);
        int p1 = atomicAdd(&cur[d0[1] >> BSHIFT], 1);
        int p2 = atomicAdd(&cur[d0[2] >> BSHIFT], 1);
        int p3 = atomicAdd(&cur[d0[3] >> BSHIFT], 1);
        int p4 = atomicAdd(&cur[d1[0] >> BSHIFT], 1);
        int p5 = atomicAdd(&cur[d1[1] >> BSHIFT], 1);
        int p6 = atomicAdd(&cur[d1[2] >> BSHIFT], 1);
        int p7 = atomicAdd(&cur[d1[3] >> BSHIFT], 1);
        ebuf[p0] = s0[0] | ((d0[0] & (NPB-1)) << 17);
        ebuf[p1] = s0[1] | ((d0[1] & (NPB-1)) << 17);
        ebuf[p2] = s0[2] | ((d0[2] & (NPB-1)) << 17);
        ebuf[p3] = s0[3] | ((d0[3] & (NPB-1)) << 17);
        ebuf[p4] = s1[0] | ((d1[0] & (NPB-1)) << 17);
        ebuf[p5] = s1[1] | ((d1[1] & (NPB-1)) << 17);
        ebuf[p6] = s1[2] | ((d1[2] & (NPB-1)) << 17);
        ebuf[p7] = s1[3] | ((d1[3] & (NPB-1)) << 17);
    }
    for (; i < iend; i += 1024) {
        i32x4 d = __builtin_nontemporal_load(&d4[i]);
        i32x4 s = __builtin_nontemporal_load(&s4[i]);
        int p0 = atomicAdd(&cur[d[0] >> BSHIFT], 1);
        int p1 = atomicAdd(&cur[d[1] >> BSHIFT], 1);
        int p2 = atomicAdd(&cur[d[2] >> BSHIFT], 1);
        int p3 = atomicAdd(&cur[d[3] >> BSHIFT], 1);
        ebuf[p0] = s[0] | ((d[0] & (NPB-1)) << 17);
        ebuf[p1] = s[1] | ((d[1] & (NPB-1)) << 17);
        ebuf[p2] = s[2] | ((d[2] & (NPB-1)) << 17);
        ebuf[p3] = s[3] | ((d[3] & (NPB-1)) << 17);
    }
}

// ---------------------------------------------------------------------------
// Per-bucket: hist over contiguous edge range — per-wave sub-hists (r8) with
// 4-edge atomic-ILP grouping (r15) -> dinv + degA -> MFMA xw (scaled by dinv).
// xws16[n][d] = int16( dinv[n] * (x[n] @ W)[d] * 2^12 ).
// ---------------------------------------------------------------------------
__global__ __launch_bounds__(256) void degxw_kernel(
    const int* __restrict__ offT, const int* __restrict__ ebuf,
    const float* __restrict__ x, const float* __restrict__ W,
    float* __restrict__ dinv, int* __restrict__ degA,
    short* __restrict__ xws16, int N, int E)
{
    __shared__ int hist4[4][72];    // per-wave sub-hists (stride 72 spreads banks)
    __shared__ float dloc[NPB];
    const int k = blockIdx.x, t = threadIdx.x;
    const int base = k << BSHIFT;
    const int wave = t >> 6;

    {
        int* hp = &hist4[0][0];
        for (int i = t; i < 4 * 72; i += 256) hp[i] = 0;
    }
    __syncthreads();
    {
        int start = offT[k * NBLK];
        int end = (k == NBUCK - 1) ? E : offT[(k + 1) * NBLK];
        int j = start + t;
        for (; j + 768 < end; j += 1024) {
            int w0 = ebuf[j];
            int w1 = ebuf[j + 256];
            int w2 = ebuf[j + 512];
            int w3 = ebuf[j + 768];
            atomicAdd(&hist4[wave][w0 >> 17], 1);
            atomicAdd(&hist4[wave][w1 >> 17], 1);
            atomicAdd(&hist4[wave][w2 >> 17], 1);
            atomicAdd(&hist4[wave][w3 >> 17], 1);
        }
        for (; j < end; j += 256)
            atomicAdd(&hist4[wave][ebuf[j] >> 17], 1);
    }
    __syncthreads();
    if (t < NPB) {
        int dd = hist4[0][t] + hist4[1][t] + hist4[2][t] + hist4[3][t];
        float dv = rsqrtf((float)(dd + 1));
        dloc[t] = dv;
        if (base + t < N) { dinv[base + t] = dv; degA[base + t] = dd; }
    }
    __syncthreads();

    // MFMA phase: wave w -> nodes base + w*16 .. +15
    const int lane = t & 63;
    const int q = lane >> 4, n = lane & 15;
    const int tile_base = base + (t >> 6) * 16;
    if (tile_base >= N) return;

    bf16x8 bfrag[4];
    #pragma unroll
    for (int i = 0; i < 4; ++i)
        #pragma unroll
        for (int j = 0; j < 8; ++j)
            bfrag[i][j] = f2bf(W[(i * 32 + q * 8 + j) * HID + n]);

    const float4* x4 = (const float4*)x;
    const int node = tile_base + n;
    f32x4 d = {0.f, 0.f, 0.f, 0.f};
    #pragma unroll
    for (int i = 0; i < 4; ++i) {
        float4 u0 = make_float4(0.f, 0.f, 0.f, 0.f), u1 = u0;
        if (node < N) {
            u0 = x4[(size_t)node * 32 + i * 8 + q * 2];
            u1 = x4[(size_t)node * 32 + i * 8 + q * 2 + 1];
        }
        bf16x8 a;
        a[0] = f2bf(u0.x); a[1] = f2bf(u0.y); a[2] = f2bf(u0.z); a[3] = f2bf(u0.w);
        a[4] = f2bf(u1.x); a[5] = f2bf(u1.y); a[6] = f2bf(u1.z); a[7] = f2bf(u1.w);
        d = __builtin_amdgcn_mfma_f32_16x16x32_bf16(a, bfrag[i], d, 0, 0, 0);
    }
    #pragma unroll
    for (int r = 0; r < 4; ++r) {
        int nd = tile_base + q * 4 + r;
        if (nd < N) {
            float val = d[r] * dloc[nd - base];
            val = fminf(7.995f, fmaxf(-7.995f, val));
            xws16[(size_t)nd * HID + n] = (short)__float2int_rn(val * FIX16);
        }
    }
}

// ---------------------------------------------------------------------------
// Per-bucket gather: direct coalesced ebuf reads (2 lanes/word), 2-lane int16
// dwordx4 gathers (8 edges in flight), ds_add_u64 accumulation with biased
// low halves (8 LDS atomics/edge). Epilogue un-biases via degA.
// ---------------------------------------------------------------------------
__global__ __launch_bounds__(256, 8) void gather_pool(
    const int* __restrict__ offT, const int* __restrict__ ebuf,
    const float* __restrict__ dinv, const int* __restrict__ degA,
    const short* __restrict__ xws16, const float* __restrict__ gcn_b,
    const int* __restrict__ batch, int* __restrict__ pool,
    int* __restrict__ cnt, int N, int E)
{
    __shared__ unsigned long long acc64[NPB * ACC64S];  // 4.5 KB
    __shared__ int lpool[16 * HID];
    __shared__ int lcnt[16];
    const int k = blockIdx.x, t = threadIdx.x;
    const int base = k << BSHIFT;

    for (int i = t; i < NPB * ACC64S; i += 256) acc64[i] = 0ull;
    lpool[t] = 0;                         // 16*HID == 256
    if (t < 16) lcnt[t] = 0;

    const int start = offT[k * NBLK];
    const int end = (k == NBUCK - 1) ? E : offT[(k + 1) * NBLK];
    const int Ek = end - start;
    __syncthreads();

    const int sub = t >> 1, h = t & 1;
    const int4* xw4 = (const int4*)xws16;
    const int* eb = ebuf + start;

    int e = sub;
    for (; e + 7 * 128 < Ek; e += 1024) {
        int w[8]; int4 vv[8];
        #pragma unroll
        for (int u = 0; u < 8; ++u) w[u] = eb[e + u * 128];
        #pragma unroll
        for (int u = 0; u < 8; ++u) vv[u] = xw4[(size_t)(w[u] & 0x1FFFF) * 2 + h];
        #pragma unroll
        for (int u = 0; u < 8; ++u) {
            unsigned long long* p = &acc64[(w[u] >> 17) * ACC64S + h * 4];
            atomicAdd(p + 0, packA(vv[u].x));
            atomicAdd(p + 1, packA(vv[u].y));
            atomicAdd(p + 2, packA(vv[u].z));
            atomicAdd(p + 3, packA(vv[u].w));
        }
    }
    for (; e < Ek; e += 128) {
        int w = eb[e];
        int4 vv = xw4[(size_t)(w & 0x1FFFF) * 2 + h];
        unsigned long long* p = &acc64[(w >> 17) * ACC64S + h * 4];
        atomicAdd(p + 0, packA(vv.x));
        atomicAdd(p + 1, packA(vv.y));
        atomicAdd(p + 2, packA(vv.z));
        atomicAdd(p + 3, packA(vv.w));
    }
    __syncthreads();

    // epilogue: un-bias + self-loop + bias + relu + pool (16-lane groups)
    int nN = min(NPB, N - base);
    int gmin = batch[base], gmax = batch[base + nN - 1];
    int range = gmax - gmin + 1;
    bool useL = (range <= 16);
    const int sub16 = t >> 4, lane16 = t & 15;
    float bb = gcn_b[lane16];

    for (int i = sub16; i < nN; i += 16) {
        int n = base + i;
        unsigned long long word = acc64[i * ACC64S + (lane16 >> 1)];
        int s = (lane16 & 1)
              ? (int)(unsigned)(word >> 32)
              : (int)(unsigned)(word & 0xFFFFFFFFull) - degA[n] * 32768;
        int tot = s + (int)xws16[(size_t)n * HID + lane16];
        float a = (float)tot * IFIX16;
        float r = fmaxf(fmaf(dinv[n], a, bb), 0.f);
        int g = batch[n];
        int ri = fx(r, FIXP);
        if (useL) {
            atomicAdd(&lpool[(g - gmin) * HID + lane16], ri);
            if (lane16 == 0) atomicAdd(&lcnt[g - gmin], 1);
        } else {
            atomicAdd(&pool[g * HID + lane16], ri);
            if (lane16 == 0) atomicAdd(&cnt[g], 1);
        }
    }
    __syncthreads();

    if (useL) {
        for (int i = t; i < range * HID; i += 256) {
            int vv = lpool[i];
            if (vv != 0) atomicAdd(&pool[gmin * HID + i], vv);
        }
        for (int i = t; i < range; i += 256) {
            int c = lcnt[i];
            if (c != 0) atomicAdd(&cnt[gmin + i], c);
        }
    }
}

// ---------------------------------------------------------------------------
// Per-graph head: one wave per graph.
// ---------------------------------------------------------------------------
__global__ __launch_bounds__(64) void head_kernel(
    const int* __restrict__ pool, const int* __restrict__ cnt,
    const float* __restrict__ mri,  const float* __restrict__ cog,
    const float* __restrict__ clin, const float* __restrict__ gen,
    const float* __restrict__ mriW, const float* __restrict__ mrib,
    const float* __restrict__ cogW, const float* __restrict__ cogb,
    const float* __restrict__ clinW, const float* __restrict__ clinb,
    const float* __restrict__ genW, const float* __restrict__ genb,
    const float* __restrict__ W1, const float* __restrict__ b1,
    const float* __restrict__ W2, const float* __restrict__ b2,
    float* __restrict__ out)
{
    const int g = blockIdx.x;
    const int lane = threadIdx.x;
    __shared__ float comb[32];
    __shared__ float h[HID];

    if (lane < HID) {
        float c = fmaxf((float)cnt[g], 1.f);
        comb[lane] = ((float)pool[g * HID + lane] * IFIXP) / c;
    }

    struct Mod { const float* in; const float* W; const float* b; int K; int off; };
    Mod mods[4] = {
        { mri  + (size_t)g * 256, mriW,  mrib,  256, 16 },
        { cog  + (size_t)g * 64,  cogW,  cogb,  64,  20 },
        { clin + (size_t)g * 32,  clinW, clinb, 32,  24 },
        { gen  + (size_t)g * 512, genW,  genb,  512, 28 },
    };
    for (int m = 0; m < 4; ++m) {
        float p0 = 0.f, p1 = 0.f, p2 = 0.f, p3 = 0.f;
        const float* in = mods[m].in;
        const float* Wm = mods[m].W;
        for (int kk = lane; kk < mods[m].K; kk += 64) {
            float xv = in[kk];
            p0 += xv * Wm[kk * 4 + 0];
            p1 += xv * Wm[kk * 4 + 1];
            p2 += xv * Wm[kk * 4 + 2];
            p3 += xv * Wm[kk * 4 + 3];
        }
        #pragma unroll
        for (int o = 32; o > 0; o >>= 1) {
            p0 += __shfl_down(p0, o);
            p1 += __shfl_down(p1, o);
            p2 += __shfl_down(p2, o);
            p3 += __shfl_down(p3, o);
        }
        if (lane == 0) {
            const float* bm = mods[m].b;
            int o = mods[m].off;
            comb[o + 0] = fmaxf(p0 + bm[0], 0.f);
            comb[o + 1] = fmaxf(p1 + bm[1], 0.f);
            comb[o + 2] = fmaxf(p2 + bm[2], 0.f);
            comb[o + 3] = fmaxf(p3 + bm[3], 0.f);
        }
    }
    __syncthreads();

    if (lane < HID) {
        float a = b1[lane];
        #pragma unroll
        for (int kk = 0; kk < 32; ++kk) a += comb[kk] * W1[kk * HID + lane];
        h[lane] = fmaxf(a, 0.f);
    }
    __syncthreads();

    if (lane == 0) {
        float l0 = b2[0], l1 = b2[1], l2 = b2[2];
        #pragma unroll
        for (int kk = 0; kk < HID; ++kk) {
            float hv = h[kk];
            l0 += hv * W2[kk * 3 + 0];
            l1 += hv * W2[kk * 3 + 1];
            l2 += hv * W2[kk * 3 + 2];
        }
        float mx = fmaxf(l0, fmaxf(l1, l2));
        float lse = mx + logf(expf(l0 - mx) + expf(l1 - mx) + expf(l2 - mx));
        out[g * 3 + 0] = l0 - lse;
        out[g * 3 + 1] = l1 - lse;
        out[g * 3 + 2] = l2 - lse;
    }
}

// ---------------------------------------------------------------------------
// Launch
// ---------------------------------------------------------------------------
extern "C" void kernel_launch(void* const* d_in, const int* in_sizes, int n_in,
                              void* d_out, int out_size, void* d_ws, size_t ws_size,
                              hipStream_t stream)
{
    const float* x     = (const float*)d_in[0];
    const int*   eidx  = (const int*)d_in[1];
    const int*   batch = (const int*)d_in[2];
    const float* mri   = (const float*)d_in[3];
    const float* cog   = (const float*)d_in[4];
    const float* clin  = (const float*)d_in[5];
    const float* gen   = (const float*)d_in[6];
    const float* gcn_W = (const float*)d_in[7];
    const float* gcn_b = (const float*)d_in[8];
    const float* mriW  = (const float*)d_in[9];
    const float* mrib  = (const float*)d_in[10];
    const float* cogW  = (const float*)d_in[11];
    const float* cogb  = (const float*)d_in[12];
    const float* clinW = (const float*)d_in[13];
    const float* clinb = (const float*)d_in[14];
    const float* genW  = (const float*)d_in[15];
    const float* genb  = (const float*)d_in[16];
    const float* W1    = (const float*)d_in[17];
    const float* b1    = (const float*)d_in[18];
    const float* W2    = (const float*)d_in[19];
    const float* b2    = (const float*)d_in[20];
    float* out = (float*)d_out;

    const int N = in_sizes[0] / NODE_DIM;   // 100000
    const int E = in_sizes[1] / 2;          // 3200000
    const int* src = eidx;
    const int* dst = eidx + E;

    // workspace layout (4-byte units)
    float* ws    = (float*)d_ws;
    short* xws16 = (short*)ws;               // N*16 int16 = 800,000 int slots
    float* dinv  = ws + 800000;              //   100,000 f
    int*   pool  = (int*)(ws + 900000);      //     4,096 i
    int*   cnt   = (int*)(ws + 904096);      //       256 i  (contiguous after pool)
    int*   offT  = (int*)(ws + 1306000);     //   400,128 i  bucket-major counts -> offsets
    int*   bsum  = (int*)(ws + 2108000);     //       256 i
    int*   ebuf  = (int*)(ws + 2109000);     // 3,200,000 i  BUCKET-MAJOR edges
    int*   degA  = (int*)(ws + 5309000);     //   100,000 i  node in-degree

    const int chunkE = (E + NBLK - 1) / NBLK;       // 12500 (mult of 4)
    const int scanNB = (TOT + 2047) / 2048;         // 196
    const int nz = N_GRAPHS * HID + N_GRAPHS;       // pool+cnt span = 4352 ints

    bucket_count<<<NBLK, 1024, 0, stream>>>(dst, offT, pool, nz, E, chunkE); // + zeroing
    scan_blocksum<<<scanNB, 256, 0, stream>>>(offT, bsum, TOT);
    scan_write2<<<scanNB, 256, 0, stream>>>(offT, bsum, TOT, scanNB);  // offT = bucket-major offsets
    bucket_scatter<<<NBLK, 1024, 0, stream>>>(src, dst, offT, ebuf, E, chunkE);
    degxw_kernel<<<NBUCK, 256, 0, stream>>>(offT, ebuf, x, gcn_W, dinv, degA, xws16, N, E);
    gather_pool<<<NBUCK, 256, 0, stream>>>(offT, ebuf, dinv, degA, xws16,
                                           gcn_b, batch, pool, cnt, N, E);
    head_kernel<<<N_GRAPHS, 64, 0, stream>>>(
        pool, cnt, mri, cog, clin, gen,
        mriW, mrib, cogW, cogb, clinW, clinb, genW, genb,
        W1, b1, W2, b2, out);
}

// Round 16
// 212.185 us; speedup vs baseline: 1.0169x; 1.0169x over previous
//
#include <hip/hip_runtime.h>
#include <hip/hip_bf16.h>
#include <math.h>

#define N_NODES   100000
#define N_EDGES   3200000
#define NODE_DIM  128
#define HID       16
#define N_GRAPHS  256

// Bucketing: 64 nodes/bucket. ebuf is BUCKET-MAJOR. Count AND scatter use the
// XCD-swizzled chunk assignment (r7/r10 wins). Count writes its histogram
// directly bucket-major (r10), zeroes pool/cnt (r12/r13), and uses 4-way
// sub-histograms (r14; r8's verified hist4 mechanism applied to the count
// site). Scatter groups 8 edges per iteration (r14: overlap LDS-atomic
// latency). Gather uses ds_add_u64 with biased low halves (r8). Scan stays
// two kernels (r12: kernel boundary < software barrier). r15's extra
// unroll/NT in count + degxw hist grouping regressed (TLP already hides
// those latencies) — reverted to the r14-verified best (213.1 us).
#define BSHIFT    6
#define NPB       64                                // nodes per bucket
#define NBUCK     ((N_NODES + NPB - 1) >> BSHIFT)   // 1563
#define NBLK      256                               // chunks in count/scatter
#define TOT       (NBUCK * NBLK)                    // 400128
#define ACC64S    9                                 // u64 acc stride (8 + pad)

// Fixed-point scales.
#define FIX16  4096.0f          // 2^12 xws int16 scale
#define IFIX16 (1.0f/4096.0f)
#define FIXP   131072.0f        // 2^17 pool scale
#define IFIXP  (1.0f/131072.0f)

__device__ __forceinline__ short f2bf(float f) {
    unsigned u = __float_as_uint(f);
    unsigned r = (u + 0x7FFF + ((u >> 16) & 1)) >> 16;
    return (short)r;
}
__device__ __forceinline__ int fx(float v, float s) { return __float2int_rn(v * s); }

// Pack an int32 holding two int16 dims into a biased u64 addend:
// low half: (lo ^ 0x8000) = lo + 32768 in [0,65535] (never borrows);
// high half: hi (two's complement accumulation exact since low never carries).
__device__ __forceinline__ unsigned long long packA(int w) {
    return ((unsigned long long)(unsigned)(w >> 16) << 32)
         | (unsigned)((w & 0xFFFF) ^ 0x8000);
}

typedef __attribute__((ext_vector_type(8))) short bf16x8;
typedef __attribute__((ext_vector_type(4))) float f32x4;
typedef __attribute__((ext_vector_type(4))) int   i32x4;

// ---------------------------------------------------------------------------
// Pass A: per-chunk bucket histogram via 4-way LDS sub-hists (selector t>>8:
// 4x less same-address atomic serialization), written DIRECTLY bucket-major:
// offT[k*NBLK + b] = count of bucket k in chunk b (XCD-swizzled b).
// Block 0 also zeroes pool/cnt (replaces the hipMemsetAsync dispatch).
// ---------------------------------------------------------------------------
__global__ __launch_bounds__(1024) void bucket_count(
    const int* __restrict__ dst, int* __restrict__ offT,
    int* __restrict__ pz, int nz, int E, int chunk)
{
    __shared__ int cnt4[4][NBUCK];       // 25 KB
    const int t = threadIdx.x;
    const int sub = t >> 8;
    const int b = (blockIdx.x & 7) * (NBLK >> 3) + (blockIdx.x >> 3);
    if (blockIdx.x == 0) {
        for (int i = t; i < nz; i += 1024) pz[i] = 0;
    }
    {
        int* cp = &cnt4[0][0];
        for (int i = t; i < 4 * NBUCK; i += 1024) cp[i] = 0;
    }
    __syncthreads();
    int e0 = b * chunk, e1 = min(E, e0 + chunk);
    if (e1 > e0) {
        const int4* d4 = (const int4*)dst;
        for (int i = (e0 >> 2) + t; i < (e1 >> 2); i += 1024) {
            int4 d = d4[i];
            atomicAdd(&cnt4[sub][d.x >> BSHIFT], 1);
            atomicAdd(&cnt4[sub][d.y >> BSHIFT], 1);
            atomicAdd(&cnt4[sub][d.z >> BSHIFT], 1);
            atomicAdd(&cnt4[sub][d.w >> BSHIFT], 1);
        }
    }
    __syncthreads();
    for (int k = t; k < NBUCK; k += 1024)
        offT[k * NBLK + b] = cnt4[0][k] + cnt4[1][k] + cnt4[2][k] + cnt4[3][k];
}

// ---------------------------------------------------------------------------
// Scan step 1: per-2048-block sums.
// ---------------------------------------------------------------------------
__global__ __launch_bounds__(256) void scan_blocksum(
    const int* __restrict__ M, int* __restrict__ bsum, int n)
{
    __shared__ int red[256];
    int t = threadIdx.x;
    int base = blockIdx.x * 2048 + t * 8;
    int s = 0;
    #pragma unroll
    for (int k = 0; k < 8; ++k) { int i = base + k; if (i < n) s += M[i]; }
    red[t] = s; __syncthreads();
    for (int o = 128; o > 0; o >>= 1) {
        if (t < o) red[t] += red[t + o];
        __syncthreads();
    }
    if (t == 0) bsum[blockIdx.x] = red[0];
}

// ---------------------------------------------------------------------------
// Scan step 2 (fused top-level): exclusive prefix, in place.
// ---------------------------------------------------------------------------
__global__ __launch_bounds__(256) void scan_write2(
    int* __restrict__ M, const int* __restrict__ bsum, int n, int nb)
{
    __shared__ int tmp[256];
    __shared__ int tsum[256];
    int t = threadIdx.x;
    tmp[t] = (t < nb) ? bsum[t] : 0;
    __syncthreads();
    for (int o = 1; o < 256; o <<= 1) {
        int a = (t >= o) ? tmp[t - o] : 0;
        __syncthreads();
        tmp[t] += a;
        __syncthreads();
    }
    const int pre0 = (blockIdx.x > 0) ? tmp[blockIdx.x - 1] : 0;

    int base = blockIdx.x * 2048 + t * 8;
    int v[8]; int s = 0;
    #pragma unroll
    for (int k = 0; k < 8; ++k) { int i = base + k; v[k] = (i < n) ? M[i] : 0; s += v[k]; }
    tsum[t] = s; __syncthreads();
    int mine = s;
    for (int o = 1; o < 256; o <<= 1) {
        int a = (t >= o) ? tsum[t - o] : 0;
        __syncthreads();
        tsum[t] += a;
        __syncthreads();
    }
    int pre = pre0 + tsum[t] - mine;
    #pragma unroll
    for (int k = 0; k < 8; ++k) {
        int i = base + k;
        if (i < n) { M[i] = pre; pre += v[k]; }
    }
}

// ---------------------------------------------------------------------------
// Pass C: bin edges into bucket-major windows. XCD-swizzled chunk index;
// cursor init reads offT transposed (strided, L2-resident). NT loads on the
// coalesced read-once src/dst streams. 8 edges per iteration: all 8 cursor
// atomics issue back-to-back (latencies overlap), then all 8 stores.
// Payload: src | (dloc << 17).
// ---------------------------------------------------------------------------
__global__ __launch_bounds__(1024) void bucket_scatter(
    const int* __restrict__ src, const int* __restrict__ dst,
    const int* __restrict__ offT, int* __restrict__ ebuf, int E, int chunk)
{
    __shared__ int cur[NBUCK];
    const int t = threadIdx.x;
    const int b = (blockIdx.x & 7) * (NBLK >> 3) + (blockIdx.x >> 3);
    for (int k = t; k < NBUCK; k += 1024) cur[k] = offT[k * NBLK + b];
    __syncthreads();
    int e0 = b * chunk, e1 = min(E, e0 + chunk);
    if (e1 <= e0) return;
    const i32x4* d4 = (const i32x4*)dst;
    const i32x4* s4 = (const i32x4*)src;
    int i = (e0 >> 2) + t;
    const int iend = (e1 >> 2);
    for (; i + 1024 < iend; i += 2048) {
        i32x4 d0 = __builtin_nontemporal_load(&d4[i]);
        i32x4 s0 = __builtin_nontemporal_load(&s4[i]);
        i32x4 d1 = __builtin_nontemporal_load(&d4[i + 1024]);
        i32x4 s1 = __builtin_nontemporal_load(&s4[i + 1024]);
        int p0 = atomicAdd(&cur[d0[0] >> BSHIFT], 1);
        int p1 = atomicAdd(&cur[d0[1] >> BSHIFT], 1);
        int p2 = atomicAdd(&cur[d0[2] >> BSHIFT], 1);
        int p3 = atomicAdd(&cur[d0[3] >> BSHIFT], 1);
        int p4 = atomicAdd(&cur[d1[0] >> BSHIFT], 1);
        int p5 = atomicAdd(&cur[d1[1] >> BSHIFT], 1);
        int p6 = atomicAdd(&cur[d1[2] >> BSHIFT], 1);
        int p7 = atomicAdd(&cur[d1[3] >> BSHIFT], 1);
        ebuf[p0] = s0[0] | ((d0[0] & (NPB-1)) << 17);
        ebuf[p1] = s0[1] | ((d0[1] & (NPB-1)) << 17);
        ebuf[p2] = s0[2] | ((d0[2] & (NPB-1)) << 17);
        ebuf[p3] = s0[3] | ((d0[3] & (NPB-1)) << 17);
        ebuf[p4] = s1[0] | ((d1[0] & (NPB-1)) << 17);
        ebuf[p5] = s1[1] | ((d1[1] & (NPB-1)) << 17);
        ebuf[p6] = s1[2] | ((d1[2] & (NPB-1)) << 17);
        ebuf[p7] = s1[3] | ((d1[3] & (NPB-1)) << 17);
    }
    for (; i < iend; i += 1024) {
        i32x4 d = __builtin_nontemporal_load(&d4[i]);
        i32x4 s = __builtin_nontemporal_load(&s4[i]);
        int p0 = atomicAdd(&cur[d[0] >> BSHIFT], 1);
        int p1 = atomicAdd(&cur[d[1] >> BSHIFT], 1);
        int p2 = atomicAdd(&cur[d[2] >> BSHIFT], 1);
        int p3 = atomicAdd(&cur[d[3] >> BSHIFT], 1);
        ebuf[p0] = s[0] | ((d[0] & (NPB-1)) << 17);
        ebuf[p1] = s[1] | ((d[1] & (NPB-1)) << 17);
        ebuf[p2] = s[2] | ((d[2] & (NPB-1)) << 17);
        ebuf[p3] = s[3] | ((d[3] & (NPB-1)) << 17);
    }
}

// ---------------------------------------------------------------------------
// Per-bucket: hist over contiguous edge range (per-wave sub-hists, 4x less
// same-address serialization) -> dinv + degA -> MFMA xw (scaled by dinv).
// xws16[n][d] = int16( dinv[n] * (x[n] @ W)[d] * 2^12 ).
// ---------------------------------------------------------------------------
__global__ __launch_bounds__(256) void degxw_kernel(
    const int* __restrict__ offT, const int* __restrict__ ebuf,
    const float* __restrict__ x, const float* __restrict__ W,
    float* __restrict__ dinv, int* __restrict__ degA,
    short* __restrict__ xws16, int N, int E)
{
    __shared__ int hist4[4][72];    // per-wave sub-hists (stride 72 spreads banks)
    __shared__ float dloc[NPB];
    const int k = blockIdx.x, t = threadIdx.x;
    const int base = k << BSHIFT;
    const int wave = t >> 6;

    {
        int* hp = &hist4[0][0];
        for (int i = t; i < 4 * 72; i += 256) hp[i] = 0;
    }
    __syncthreads();
    {
        int start = offT[k * NBLK];
        int end = (k == NBUCK - 1) ? E : offT[(k + 1) * NBLK];
        for (int j = start + t; j < end; j += 256)
            atomicAdd(&hist4[wave][ebuf[j] >> 17], 1);
    }
    __syncthreads();
    if (t < NPB) {
        int dd = hist4[0][t] + hist4[1][t] + hist4[2][t] + hist4[3][t];
        float dv = rsqrtf((float)(dd + 1));
        dloc[t] = dv;
        if (base + t < N) { dinv[base + t] = dv; degA[base + t] = dd; }
    }
    __syncthreads();

    // MFMA phase: wave w -> nodes base + w*16 .. +15
    const int lane = t & 63;
    const int q = lane >> 4, n = lane & 15;
    const int tile_base = base + (t >> 6) * 16;
    if (tile_base >= N) return;

    bf16x8 bfrag[4];
    #pragma unroll
    for (int i = 0; i < 4; ++i)
        #pragma unroll
        for (int j = 0; j < 8; ++j)
            bfrag[i][j] = f2bf(W[(i * 32 + q * 8 + j) * HID + n]);

    const float4* x4 = (const float4*)x;
    const int node = tile_base + n;
    f32x4 d = {0.f, 0.f, 0.f, 0.f};
    #pragma unroll
    for (int i = 0; i < 4; ++i) {
        float4 u0 = make_float4(0.f, 0.f, 0.f, 0.f), u1 = u0;
        if (node < N) {
            u0 = x4[(size_t)node * 32 + i * 8 + q * 2];
            u1 = x4[(size_t)node * 32 + i * 8 + q * 2 + 1];
        }
        bf16x8 a;
        a[0] = f2bf(u0.x); a[1] = f2bf(u0.y); a[2] = f2bf(u0.z); a[3] = f2bf(u0.w);
        a[4] = f2bf(u1.x); a[5] = f2bf(u1.y); a[6] = f2bf(u1.z); a[7] = f2bf(u1.w);
        d = __builtin_amdgcn_mfma_f32_16x16x32_bf16(a, bfrag[i], d, 0, 0, 0);
    }
    #pragma unroll
    for (int r = 0; r < 4; ++r) {
        int nd = tile_base + q * 4 + r;
        if (nd < N) {
            float val = d[r] * dloc[nd - base];
            val = fminf(7.995f, fmaxf(-7.995f, val));
            xws16[(size_t)nd * HID + n] = (short)__float2int_rn(val * FIX16);
        }
    }
}

// ---------------------------------------------------------------------------
// Per-bucket gather: direct coalesced ebuf reads (2 lanes/word), 2-lane int16
// dwordx4 gathers (8 edges in flight), ds_add_u64 accumulation with biased
// low halves (8 LDS atomics/edge). Epilogue un-biases via degA.
// ---------------------------------------------------------------------------
__global__ __launch_bounds__(256, 8) void gather_pool(
    const int* __restrict__ offT, const int* __restrict__ ebuf,
    const float* __restrict__ dinv, const int* __restrict__ degA,
    const short* __restrict__ xws16, const float* __restrict__ gcn_b,
    const int* __restrict__ batch, int* __restrict__ pool,
    int* __restrict__ cnt, int N, int E)
{
    __shared__ unsigned long long acc64[NPB * ACC64S];  // 4.5 KB
    __shared__ int lpool[16 * HID];
    __shared__ int lcnt[16];
    const int k = blockIdx.x, t = threadIdx.x;
    const int base = k << BSHIFT;

    for (int i = t; i < NPB * ACC64S; i += 256) acc64[i] = 0ull;
    lpool[t] = 0;                         // 16*HID == 256
    if (t < 16) lcnt[t] = 0;

    const int start = offT[k * NBLK];
    const int end = (k == NBUCK - 1) ? E : offT[(k + 1) * NBLK];
    const int Ek = end - start;
    __syncthreads();

    const int sub = t >> 1, h = t & 1;
    const int4* xw4 = (const int4*)xws16;
    const int* eb = ebuf + start;

    int e = sub;
    for (; e + 7 * 128 < Ek; e += 1024) {
        int w[8]; int4 vv[8];
        #pragma unroll
        for (int u = 0; u < 8; ++u) w[u] = eb[e + u * 128];
        #pragma unroll
        for (int u = 0; u < 8; ++u) vv[u] = xw4[(size_t)(w[u] & 0x1FFFF) * 2 + h];
        #pragma unroll
        for (int u = 0; u < 8; ++u) {
            unsigned long long* p = &acc64[(w[u] >> 17) * ACC64S + h * 4];
            atomicAdd(p + 0, packA(vv[u].x));
            atomicAdd(p + 1, packA(vv[u].y));
            atomicAdd(p + 2, packA(vv[u].z));
            atomicAdd(p + 3, packA(vv[u].w));
        }
    }
    for (; e < Ek; e += 128) {
        int w = eb[e];
        int4 vv = xw4[(size_t)(w & 0x1FFFF) * 2 + h];
        unsigned long long* p = &acc64[(w >> 17) * ACC64S + h * 4];
        atomicAdd(p + 0, packA(vv.x));
        atomicAdd(p + 1, packA(vv.y));
        atomicAdd(p + 2, packA(vv.z));
        atomicAdd(p + 3, packA(vv.w));
    }
    __syncthreads();

    // epilogue: un-bias + self-loop + bias + relu + pool (16-lane groups)
    int nN = min(NPB, N - base);
    int gmin = batch[base], gmax = batch[base + nN - 1];
    int range = gmax - gmin + 1;
    bool useL = (range <= 16);
    const int sub16 = t >> 4, lane16 = t & 15;
    float bb = gcn_b[lane16];

    for (int i = sub16; i < nN; i += 16) {
        int n = base + i;
        unsigned long long word = acc64[i * ACC64S + (lane16 >> 1)];
        int s = (lane16 & 1)
              ? (int)(unsigned)(word >> 32)
              : (int)(unsigned)(word & 0xFFFFFFFFull) - degA[n] * 32768;
        int tot = s + (int)xws16[(size_t)n * HID + lane16];
        float a = (float)tot * IFIX16;
        float r = fmaxf(fmaf(dinv[n], a, bb), 0.f);
        int g = batch[n];
        int ri = fx(r, FIXP);
        if (useL) {
            atomicAdd(&lpool[(g - gmin) * HID + lane16], ri);
            if (lane16 == 0) atomicAdd(&lcnt[g - gmin], 1);
        } else {
            atomicAdd(&pool[g * HID + lane16], ri);
            if (lane16 == 0) atomicAdd(&cnt[g], 1);
        }
    }
    __syncthreads();

    if (useL) {
        for (int i = t; i < range * HID; i += 256) {
            int vv = lpool[i];
            if (vv != 0) atomicAdd(&pool[gmin * HID + i], vv);
        }
        for (int i = t; i < range; i += 256) {
            int c = lcnt[i];
            if (c != 0) atomicAdd(&cnt[gmin + i], c);
        }
    }
}

// ---------------------------------------------------------------------------
// Per-graph head: one wave per graph.
// ---------------------------------------------------------------------------
__global__ __launch_bounds__(64) void head_kernel(
    const int* __restrict__ pool, const int* __restrict__ cnt,
    const float* __restrict__ mri,  const float* __restrict__ cog,
    const float* __restrict__ clin, const float* __restrict__ gen,
    const float* __restrict__ mriW, const float* __restrict__ mrib,
    const float* __restrict__ cogW, const float* __restrict__ cogb,
    const float* __restrict__ clinW, const float* __restrict__ clinb,
    const float* __restrict__ genW, const float* __restrict__ genb,
    const float* __restrict__ W1, const float* __restrict__ b1,
    const float* __restrict__ W2, const float* __restrict__ b2,
    float* __restrict__ out)
{
    const int g = blockIdx.x;
    const int lane = threadIdx.x;
    __shared__ float comb[32];
    __shared__ float h[HID];

    if (lane < HID) {
        float c = fmaxf((float)cnt[g], 1.f);
        comb[lane] = ((float)pool[g * HID + lane] * IFIXP) / c;
    }

    struct Mod { const float* in; const float* W; const float* b; int K; int off; };
    Mod mods[4] = {
        { mri  + (size_t)g * 256, mriW,  mrib,  256, 16 },
        { cog  + (size_t)g * 64,  cogW,  cogb,  64,  20 },
        { clin + (size_t)g * 32,  clinW, clinb, 32,  24 },
        { gen  + (size_t)g * 512, genW,  genb,  512, 28 },
    };
    for (int m = 0; m < 4; ++m) {
        float p0 = 0.f, p1 = 0.f, p2 = 0.f, p3 = 0.f;
        const float* in = mods[m].in;
        const float* Wm = mods[m].W;
        for (int kk = lane; kk < mods[m].K; kk += 64) {
            float xv = in[kk];
            p0 += xv * Wm[kk * 4 + 0];
            p1 += xv * Wm[kk * 4 + 1];
            p2 += xv * Wm[kk * 4 + 2];
            p3 += xv * Wm[kk * 4 + 3];
        }
        #pragma unroll
        for (int o = 32; o > 0; o >>= 1) {
            p0 += __shfl_down(p0, o);
            p1 += __shfl_down(p1, o);
            p2 += __shfl_down(p2, o);
            p3 += __shfl_down(p3, o);
        }
        if (lane == 0) {
            const float* bm = mods[m].b;
            int o = mods[m].off;
            comb[o + 0] = fmaxf(p0 + bm[0], 0.f);
            comb[o + 1] = fmaxf(p1 + bm[1], 0.f);
            comb[o + 2] = fmaxf(p2 + bm[2], 0.f);
            comb[o + 3] = fmaxf(p3 + bm[3], 0.f);
        }
    }
    __syncthreads();

    if (lane < HID) {
        float a = b1[lane];
        #pragma unroll
        for (int kk = 0; kk < 32; ++kk) a += comb[kk] * W1[kk * HID + lane];
        h[lane] = fmaxf(a, 0.f);
    }
    __syncthreads();

    if (lane == 0) {
        float l0 = b2[0], l1 = b2[1], l2 = b2[2];
        #pragma unroll
        for (int kk = 0; kk < HID; ++kk) {
            float hv = h[kk];
            l0 += hv * W2[kk * 3 + 0];
            l1 += hv * W2[kk * 3 + 1];
            l2 += hv * W2[kk * 3 + 2];
        }
        float mx = fmaxf(l0, fmaxf(l1, l2));
        float lse = mx + logf(expf(l0 - mx) + expf(l1 - mx) + expf(l2 - mx));
        out[g * 3 + 0] = l0 - lse;
        out[g * 3 + 1] = l1 - lse;
        out[g * 3 + 2] = l2 - lse;
    }
}

// ---------------------------------------------------------------------------
// Launch
// ---------------------------------------------------------------------------
extern "C" void kernel_launch(void* const* d_in, const int* in_sizes, int n_in,
                              void* d_out, int out_size, void* d_ws, size_t ws_size,
                              hipStream_t stream)
{
    const float* x     = (const float*)d_in[0];
    const int*   eidx  = (const int*)d_in[1];
    const int*   batch = (const int*)d_in[2];
    const float* mri   = (const float*)d_in[3];
    const float* cog   = (const float*)d_in[4];
    const float* clin  = (const float*)d_in[5];
    const float* gen   = (const float*)d_in[6];
    const float* gcn_W = (const float*)d_in[7];
    const float* gcn_b = (const float*)d_in[8];
    const float* mriW  = (const float*)d_in[9];
    const float* mrib  = (const float*)d_in[10];
    const float* cogW  = (const float*)d_in[11];
    const float* cogb  = (const float*)d_in[12];
    const float* clinW = (const float*)d_in[13];
    const float* clinb = (const float*)d_in[14];
    const float* genW  = (const float*)d_in[15];
    const float* genb  = (const float*)d_in[16];
    const float* W1    = (const float*)d_in[17];
    const float* b1    = (const float*)d_in[18];
    const float* W2    = (const float*)d_in[19];
    const float* b2    = (const float*)d_in[20];
    float* out = (float*)d_out;

    const int N = in_sizes[0] / NODE_DIM;   // 100000
    const int E = in_sizes[1] / 2;          // 3200000
    const int* src = eidx;
    const int* dst = eidx + E;

    // workspace layout (4-byte units)
    float* ws    = (float*)d_ws;
    short* xws16 = (short*)ws;               // N*16 int16 = 800,000 int slots
    float* dinv  = ws + 800000;              //   100,000 f
    int*   pool  = (int*)(ws + 900000);      //     4,096 i
    int*   cnt   = (int*)(ws + 904096);      //       256 i  (contiguous after pool)
    int*   offT  = (int*)(ws + 1306000);     //   400,128 i  bucket-major counts -> offsets
    int*   bsum  = (int*)(ws + 2108000);     //       256 i
    int*   ebuf  = (int*)(ws + 2109000);     // 3,200,000 i  BUCKET-MAJOR edges
    int*   degA  = (int*)(ws + 5309000);     //   100,000 i  node in-degree

    const int chunkE = (E + NBLK - 1) / NBLK;       // 12500 (mult of 4)
    const int scanNB = (TOT + 2047) / 2048;         // 196
    const int nz = N_GRAPHS * HID + N_GRAPHS;       // pool+cnt span = 4352 ints

    bucket_count<<<NBLK, 1024, 0, stream>>>(dst, offT, pool, nz, E, chunkE); // + zeroing
    scan_blocksum<<<scanNB, 256, 0, stream>>>(offT, bsum, TOT);
    scan_write2<<<scanNB, 256, 0, stream>>>(offT, bsum, TOT, scanNB);  // offT = bucket-major offsets
    bucket_scatter<<<NBLK, 1024, 0, stream>>>(src, dst, offT, ebuf, E, chunkE);
    degxw_kernel<<<NBUCK, 256, 0, stream>>>(offT, ebuf, x, gcn_W, dinv, degA, xws16, N, E);
    gather_pool<<<NBUCK, 256, 0, stream>>>(offT, ebuf, dinv, degA, xws16,
                                           gcn_b, batch, pool, cnt, N, E);
    head_kernel<<<N_GRAPHS, 64, 0, stream>>>(
        pool, cnt, mri, cog, clin, gen,
        mriW, mrib, cogW, cogb, clinW, clinb, genW, genb,
        W1, b1, W2, b2, out);
}